// Round 2
// baseline (13513.933 us; speedup 1.0000x reference)
//
#include <hip/hip_runtime.h>
#include <hip/hip_bf16.h>

#define TT 512
#define BB 64
#define DD 512
#define HH 512
#define NWG 64
#define NTH 512
#define SPIN_MAX 4000000

typedef short bf16x8 __attribute__((ext_vector_type(8)));
typedef float f32x4 __attribute__((ext_vector_type(4)));
typedef float float4_ __attribute__((ext_vector_type(4)));
typedef unsigned short us4 __attribute__((ext_vector_type(4)));
typedef unsigned short ushort_t;

__device__ __forceinline__ ushort_t f2bf(float f) {
    unsigned u = __float_as_uint(f);
    u = (u + 0x7fffu + ((u >> 16) & 1u)) >> 16;   // RNE
    return (ushort_t)u;
}

__device__ __forceinline__ bf16x8 cvt8(const float* __restrict__ p) {
    float4_ u0 = *(const float4_*)(p);
    float4_ u1 = *(const float4_*)(p + 4);
    bf16x8 a;
    a[0] = (short)f2bf(u0.x); a[1] = (short)f2bf(u0.y);
    a[2] = (short)f2bf(u0.z); a[3] = (short)f2bf(u0.w);
    a[4] = (short)f2bf(u1.x); a[5] = (short)f2bf(u1.y);
    a[6] = (short)f2bf(u1.z); a[7] = (short)f2bf(u1.w);
    return a;
}

__device__ __forceinline__ float fast_sigmoid(float x) {
    return __builtin_amdgcn_rcpf(1.f + __expf(-x));
}
__device__ __forceinline__ float fast_tanh(float x) {
    return 2.f * __builtin_amdgcn_rcpf(1.f + __expf(-2.f * x)) - 1.f;
}

// ---------------- x f32 -> bf16 pre-conversion ----------------
__global__ void cvt_x(const float* __restrict__ in, ushort_t* __restrict__ outp, int n) {
    int idx = (blockIdx.x * blockDim.x + threadIdx.x) * 4;
    int stride = gridDim.x * blockDim.x * 4;
    for (int i = idx; i < n; i += stride) {
        float4_ v = *(const float4_*)(in + i);
        us4 o;
        o.x = f2bf(v.x); o.y = f2bf(v.y); o.z = f2bf(v.z); o.w = f2bf(v.w);
        *(us4*)(outp + i) = o;
    }
}

// ---------------- LSTM kernel ----------------
// MODE 0: persistent, x pre-converted to bf16 in ws.
// MODE 1: persistent, x converted inline from f32.
// MODE 2: one step per launch (t0..t1), no grid barrier, no ws use:
//         h read from out (f32), c carried in out's cT slot.
//
// 64 WGs x 512 threads. WG wg owns h-cols [wg*8, wg*8+8) for all 64 batch rows.
// Wave wid: kh = wid>>1 (K-slice of 256), mp = wid&1 (32-row half).
// Weights for the WG's 32 gate-cols ([1024 K x 32 n] bf16) live in registers.
template<int MODE>
__global__ __launch_bounds__(NTH)
void lstm_kernel(const float* __restrict__ x,
                 const ushort_t* __restrict__ xbf,
                 const float* __restrict__ Wf, const float* __restrict__ bfp,
                 const float* __restrict__ Wi, const float* __restrict__ bip,
                 const float* __restrict__ Wg, const float* __restrict__ bgp,
                 const float* __restrict__ Wo, const float* __restrict__ bop,
                 float* __restrict__ out,
                 unsigned* __restrict__ ctr,
                 ushort_t* __restrict__ hbuf,
                 int t0, int t1)
{
    const int tid = threadIdx.x;
    const int wg  = blockIdx.x;
    const int l   = tid & 63;
    const int wid = tid >> 6;
    const int kh  = wid >> 1;          // 0..3  K-slice (0,1 = x part; 2,3 = h part)
    const int mp  = wid & 1;           // 0..1  row half (32 rows)
    const int l15 = l & 15;
    const int lg  = l >> 4;            // 0..3
    const int sub = lg * 8;            // k sub-offset within a k-step

    __shared__ float P[3][BB * 32];    // partial sums from kh=1..3
    __shared__ float G[BB * 32];       // final gates

    // ---- load this wave's B fragments (weights) into registers, once ----
    bf16x8 bfr[8][2];
    {
        #pragma unroll
        for (int nt = 0; nt < 2; ++nt) {
            int n = nt * 16 + l15;                       // 0..31 panel col
            const float* wmat = (n >> 3) == 0 ? Wf :
                                ((n >> 3) == 1 ? Wi :
                                ((n >> 3) == 2 ? Wg : Wo));
            const float* wrow = wmat + (size_t)(wg * 8 + (n & 7)) * (DD + HH);
            #pragma unroll
            for (int ks = 0; ks < 8; ++ks) {
                int k = kh * 256 + ks * 32 + sub;
                bfr[ks][nt] = cvt8(wrow + k);
            }
        }
    }

    // activation-phase mapping: one (batch, hcol) per thread
    const int b_act = tid >> 3;        // 0..63
    const int j_act = tid & 7;         // 0..7
    const float bfv = bfp[wg * 8 + j_act];
    const float biv = bip[wg * 8 + j_act];
    const float bgv = bgp[wg * 8 + j_act];
    const float bov = bop[wg * 8 + j_act];

    float c_state, h_last = 0.f;
    if constexpr (MODE < 2) {
        c_state = 0.f;
    } else {
        c_state = (t0 == 0) ? 0.f
                : out[(size_t)TT * BB * HH + BB * HH + (size_t)b_act * HH + wg * 8 + j_act];
    }

    const int aRow = mp * 32 + l15;    // A row for mtl=0 (mtl=1 adds 16)
    int dead = 0;

    for (int t = t0; t < t1; ++t) {
        f32x4 acc[2][2];
        #pragma unroll
        for (int m = 0; m < 2; ++m)
            #pragma unroll
            for (int n = 0; n < 2; ++n)
                acc[m][n] = (f32x4){0.f, 0.f, 0.f, 0.f};

        // ---- select A source for this wave ----
        const ushort_t* apb = nullptr;
        const float*    apf = nullptr;
        bool doM = true;
        if (kh < 2) {
            if constexpr (MODE == 0)
                apb = xbf + (size_t)t * (BB * DD) + (size_t)aRow * DD + kh * 256 + sub;
            else
                apf = x + ((size_t)t * BB + aRow) * DD + kh * 256 + sub;
        } else {
            if constexpr (MODE < 2)
                apb = hbuf + (size_t)(t & 1) * (BB * HH) + (size_t)aRow * HH + (kh - 2) * 256 + sub;
            else {
                if (t == 0) doM = false;
                else apf = out + ((size_t)(t - 1) * BB + aRow) * HH + (kh - 2) * 256 + sub;
            }
        }

        if (doM) {
            if (apb) {
                #pragma unroll
                for (int ks = 0; ks < 8; ++ks) {
                    bf16x8 a0 = *(const bf16x8*)(apb + ks * 32);
                    bf16x8 a1 = *(const bf16x8*)(apb + 16 * 512 + ks * 32);
                    acc[0][0] = __builtin_amdgcn_mfma_f32_16x16x32_bf16(a0, bfr[ks][0], acc[0][0], 0, 0, 0);
                    acc[0][1] = __builtin_amdgcn_mfma_f32_16x16x32_bf16(a0, bfr[ks][1], acc[0][1], 0, 0, 0);
                    acc[1][0] = __builtin_amdgcn_mfma_f32_16x16x32_bf16(a1, bfr[ks][0], acc[1][0], 0, 0, 0);
                    acc[1][1] = __builtin_amdgcn_mfma_f32_16x16x32_bf16(a1, bfr[ks][1], acc[1][1], 0, 0, 0);
                }
            } else {
                #pragma unroll
                for (int ks = 0; ks < 8; ++ks) {
                    bf16x8 a0 = cvt8(apf + ks * 32);
                    bf16x8 a1 = cvt8(apf + 16 * 512 + ks * 32);
                    acc[0][0] = __builtin_amdgcn_mfma_f32_16x16x32_bf16(a0, bfr[ks][0], acc[0][0], 0, 0, 0);
                    acc[0][1] = __builtin_amdgcn_mfma_f32_16x16x32_bf16(a0, bfr[ks][1], acc[0][1], 0, 0, 0);
                    acc[1][0] = __builtin_amdgcn_mfma_f32_16x16x32_bf16(a1, bfr[ks][0], acc[1][0], 0, 0, 0);
                    acc[1][1] = __builtin_amdgcn_mfma_f32_16x16x32_bf16(a1, bfr[ks][1], acc[1][1], 0, 0, 0);
                }
            }
        }

        // ---- cross-wave K reduction (4-way) ----
        if (kh > 0) {
            #pragma unroll
            for (int mtl = 0; mtl < 2; ++mtl)
                #pragma unroll
                for (int nt = 0; nt < 2; ++nt)
                    #pragma unroll
                    for (int r = 0; r < 4; ++r) {
                        int row = mp * 32 + mtl * 16 + lg * 4 + r;
                        P[kh - 1][row * 32 + nt * 16 + l15] = acc[mtl][nt][r];
                    }
        }
        __syncthreads();
        if (kh == 0) {
            #pragma unroll
            for (int mtl = 0; mtl < 2; ++mtl)
                #pragma unroll
                for (int nt = 0; nt < 2; ++nt)
                    #pragma unroll
                    for (int r = 0; r < 4; ++r) {
                        int row = mp * 32 + mtl * 16 + lg * 4 + r;
                        int idx = row * 32 + nt * 16 + l15;
                        G[idx] = acc[mtl][nt][r] + P[0][idx] + P[1][idx] + P[2][idx];
                    }
        }
        __syncthreads();

        // ---- activations: thread owns (b_act, hcol = wg*8 + j_act) ----
        {
            float gf = G[b_act * 32 +      j_act] + bfv;
            float gi = G[b_act * 32 +  8 + j_act] + biv;
            float gg = G[b_act * 32 + 16 + j_act] + bgv;
            float go = G[b_act * 32 + 24 + j_act] + bov;
            float fg = fast_sigmoid(gf);
            float ig = fast_sigmoid(gi);
            float g2 = fast_tanh(gg);
            float og = fast_sigmoid(go);
            c_state = fg * c_state + ig * g2;
            float hv = og * fast_tanh(c_state);
            h_last = hv;
            out[((size_t)t * BB + b_act) * HH + wg * 8 + j_act] = hv;
            if constexpr (MODE < 2)
                hbuf[(size_t)((t & 1) ^ 1) * (BB * HH) + b_act * HH + wg * 8 + j_act] = f2bf(hv);
        }

        // ---- grid barrier (persistent modes only; bounded spin) ----
        if constexpr (MODE < 2) {
            if (t != TT - 1) {
                __threadfence();        // release: h writes visible device-wide
                __syncthreads();
                if (tid == 0) {
                    __hip_atomic_fetch_add(&ctr[t], 1u, __ATOMIC_RELEASE, __HIP_MEMORY_SCOPE_AGENT);
                    if (!dead) {
                        int it = 0;
                        while (__hip_atomic_load(&ctr[t], __ATOMIC_RELAXED, __HIP_MEMORY_SCOPE_AGENT) < NWG) {
                            __builtin_amdgcn_s_sleep(8);
                            if (++it > SPIN_MAX) { dead = 1; break; }
                        }
                    }
                }
                __syncthreads();
                __threadfence();        // acquire: drop stale cached h
            }
        }
    }

    // ---- hT, cT ----
    {
        size_t base = (size_t)TT * BB * HH;
        out[base + (size_t)b_act * HH + wg * 8 + j_act] = h_last;
        out[base + BB * HH + (size_t)b_act * HH + wg * 8 + j_act] = c_state;
    }
}

extern "C" void kernel_launch(void* const* d_in, const int* in_sizes, int n_in,
                              void* d_out, int out_size, void* d_ws, size_t ws_size,
                              hipStream_t stream) {
    const float* x   = (const float*)d_in[0];
    const float* Wf  = (const float*)d_in[1];
    const float* bf_ = (const float*)d_in[2];
    const float* Wi  = (const float*)d_in[3];
    const float* bi_ = (const float*)d_in[4];
    const float* Wg  = (const float*)d_in[5];
    const float* bg_ = (const float*)d_in[6];
    const float* Wo  = (const float*)d_in[7];
    const float* bo_ = (const float*)d_in[8];
    float* out = (float*)d_out;

    unsigned*  ctr  = (unsigned*)d_ws;                         // 512 * 4 B
    ushort_t*  hbuf = (ushort_t*)((char*)d_ws + 4096);         // 2 * 64*512 bf16
    ushort_t*  xbf  = (ushort_t*)((char*)d_ws + 262144);       // T*B*D bf16 (32 MB)

    const size_t need_small = 4096 + 2 * BB * HH * sizeof(ushort_t);      // 136 KB
    const size_t need_full  = 262144 + (size_t)TT * BB * DD * sizeof(ushort_t);

    if (ws_size >= need_full) {
        hipMemsetAsync(d_ws, 0, need_small, stream);
        cvt_x<<<2048, 256, 0, stream>>>(x, xbf, TT * BB * DD);
        lstm_kernel<0><<<NWG, NTH, 0, stream>>>(x, xbf, Wf, bf_, Wi, bi_, Wg, bg_,
                                                Wo, bo_, out, ctr, hbuf, 0, TT);
    } else if (ws_size >= need_small) {
        hipMemsetAsync(d_ws, 0, need_small, stream);
        lstm_kernel<1><<<NWG, NTH, 0, stream>>>(x, xbf, Wf, bf_, Wi, bi_, Wg, bg_,
                                                Wo, bo_, out, ctr, hbuf, 0, TT);
    } else {
        // zero-workspace safety net: one launch per time step, stream-ordered
        for (int t = 0; t < TT; ++t)
            lstm_kernel<2><<<NWG, NTH, 0, stream>>>(x, xbf, Wf, bf_, Wi, bi_, Wg, bg_,
                                                    Wo, bo_, out, ctr, hbuf, t, t + 1);
    }
}

// Round 3
// 2967.274 us; speedup vs baseline: 4.5543x; 4.5543x over previous
//
#include <hip/hip_runtime.h>
#include <hip/hip_bf16.h>

#define TT 512
#define BB 64
#define DD 512
#define HH 512
#define NWG 64
#define NTH 512
#define SPIN_MAX 1000000
#define PSTR 33            // padded LDS row stride (bank-conflict-free)
#define HB_ELEMS (BB * HH) // 32768 elems per h buffer

typedef short bf16x8 __attribute__((ext_vector_type(8)));
typedef float f32x4 __attribute__((ext_vector_type(4)));
typedef float float4_ __attribute__((ext_vector_type(4)));
typedef unsigned short us4 __attribute__((ext_vector_type(4)));
typedef unsigned short ushort_t;

__device__ __forceinline__ ushort_t f2bf(float f) {
    unsigned u = __float_as_uint(f);
    u = (u + 0x7fffu + ((u >> 16) & 1u)) >> 16;   // RNE
    return (ushort_t)u;
}

__device__ __forceinline__ bf16x8 cvt8(const float* __restrict__ p) {
    float4_ u0 = *(const float4_*)(p);
    float4_ u1 = *(const float4_*)(p + 4);
    bf16x8 a;
    a[0] = (short)f2bf(u0.x); a[1] = (short)f2bf(u0.y);
    a[2] = (short)f2bf(u0.z); a[3] = (short)f2bf(u0.w);
    a[4] = (short)f2bf(u1.x); a[5] = (short)f2bf(u1.y);
    a[6] = (short)f2bf(u1.z); a[7] = (short)f2bf(u1.w);
    return a;
}

__device__ __forceinline__ float fast_sigmoid(float x) {
    return __builtin_amdgcn_rcpf(1.f + __expf(-x));
}
__device__ __forceinline__ float fast_tanh(float x) {
    return 2.f * __builtin_amdgcn_rcpf(1.f + __expf(-2.f * x)) - 1.f;
}

// Coherent (cross-XCD) 16B load: bypass L1+L2, served by shared L3.
__device__ __forceinline__ bf16x8 load_coh16(const ushort_t* p) {
    bf16x8 r;
    asm volatile("global_load_dwordx4 %0, %1, off sc0 sc1" : "=v"(r) : "v"(p));
    return r;
}
// Coherent 2B store: write through to L3.
__device__ __forceinline__ void store_coh2(ushort_t* p, unsigned v) {
    asm volatile("global_store_short %0, %1, off sc0 sc1" :: "v"(p), "v"(v) : "memory");
}

// ---------------- x f32 -> bf16 pre-conversion ----------------
__global__ void cvt_x(const float* __restrict__ in, ushort_t* __restrict__ outp, int n) {
    int idx = (blockIdx.x * blockDim.x + threadIdx.x) * 4;
    int stride = gridDim.x * blockDim.x * 4;
    for (int i = idx; i < n; i += stride) {
        float4_ v = *(const float4_*)(in + i);
        us4 o;
        o.x = f2bf(v.x); o.y = f2bf(v.y); o.z = f2bf(v.z); o.w = f2bf(v.w);
        *(us4*)(outp + i) = o;
    }
}

// ---------------- LSTM kernel ----------------
// MODE 0: persistent, x pre-converted to bf16 in ws.
// MODE 1: persistent, x converted inline from f32.
// MODE 2: one step per launch, no grid barrier, h read from out (f32).
//
// 64 WGs x 512 threads. WG wg owns h-cols [wg*8, wg*8+8) for all 64 batch rows.
// Wave wid: kh = wid>>1 (K-slice of 256), mp = wid&1 (32-row half).
// Weights for the WG's 32 gate-cols ([1024 K x 32 n] bf16) live in registers.
// hbuf layout (bf16): elem = (hcol>>3)*512 + row*8 + (hcol&7), double-buffered.
template<int MODE>
__global__ __launch_bounds__(NTH)
void lstm_kernel(const float* __restrict__ x,
                 const ushort_t* __restrict__ xbf,
                 const float* __restrict__ Wf, const float* __restrict__ bfp,
                 const float* __restrict__ Wi, const float* __restrict__ bip,
                 const float* __restrict__ Wg, const float* __restrict__ bgp,
                 const float* __restrict__ Wo, const float* __restrict__ bop,
                 float* __restrict__ out,
                 unsigned* __restrict__ ctr,
                 ushort_t* __restrict__ hbuf,
                 int t0, int t1)
{
    const int tid = threadIdx.x;
    const int wg  = blockIdx.x;
    const int l   = tid & 63;
    const int wid = tid >> 6;
    const int kh  = wid >> 1;          // 0..3  K-slice (0,1 = x part; 2,3 = h part)
    const int mp  = wid & 1;           // 0..1  row half (32 rows)
    const int l15 = l & 15;
    const int lg  = l >> 4;            // 0..3
    const int sub = lg * 8;            // k sub-offset within a k-step

    __shared__ float P[3][BB * PSTR];  // partial sums from kh=1..3
    __shared__ float G[BB * PSTR];     // final gates

    // ---- load this wave's B fragments (weights) into registers, once ----
    bf16x8 bfr[8][2];
    {
        #pragma unroll
        for (int nt = 0; nt < 2; ++nt) {
            int n = nt * 16 + l15;                       // 0..31 panel col
            const float* wmat = (n >> 3) == 0 ? Wf :
                                ((n >> 3) == 1 ? Wi :
                                ((n >> 3) == 2 ? Wg : Wo));
            const float* wrow = wmat + (size_t)(wg * 8 + (n & 7)) * (DD + HH);
            #pragma unroll
            for (int ks = 0; ks < 8; ++ks) {
                int k = kh * 256 + ks * 32 + sub;
                bfr[ks][nt] = cvt8(wrow + k);
            }
        }
    }

    // activation-phase mapping: one (batch, hcol) per thread
    const int b_act = tid >> 3;        // 0..63
    const int j_act = tid & 7;         // 0..7
    const float bfv = bfp[wg * 8 + j_act];
    const float biv = bip[wg * 8 + j_act];
    const float bgv = bgp[wg * 8 + j_act];
    const float bov = bop[wg * 8 + j_act];

    float c_state, h_last = 0.f;
    if constexpr (MODE < 2) {
        c_state = 0.f;
    } else {
        c_state = (t0 == 0) ? 0.f
                : out[(size_t)TT * BB * HH + BB * HH + (size_t)b_act * HH + wg * 8 + j_act];
    }

    const int aRow = mp * 32 + l15;    // A row for mtl=0 (mtl=1 adds 16)
    int dead = 0;

    for (int t = t0; t < t1; ++t) {
        f32x4 acc[2][2];
        #pragma unroll
        for (int m = 0; m < 2; ++m)
            #pragma unroll
            for (int n = 0; n < 2; ++n)
                acc[m][n] = (f32x4){0.f, 0.f, 0.f, 0.f};

        if (kh < 2) {
            // ---- x half of K ----
            if constexpr (MODE == 0) {
                const ushort_t* ap = xbf + (size_t)t * (BB * DD) + (size_t)aRow * DD + kh * 256 + sub;
                #pragma unroll
                for (int ks = 0; ks < 8; ++ks) {
                    bf16x8 a0 = *(const bf16x8*)(ap + ks * 32);
                    bf16x8 a1 = *(const bf16x8*)(ap + 16 * DD + ks * 32);
                    acc[0][0] = __builtin_amdgcn_mfma_f32_16x16x32_bf16(a0, bfr[ks][0], acc[0][0], 0, 0, 0);
                    acc[0][1] = __builtin_amdgcn_mfma_f32_16x16x32_bf16(a0, bfr[ks][1], acc[0][1], 0, 0, 0);
                    acc[1][0] = __builtin_amdgcn_mfma_f32_16x16x32_bf16(a1, bfr[ks][0], acc[1][0], 0, 0, 0);
                    acc[1][1] = __builtin_amdgcn_mfma_f32_16x16x32_bf16(a1, bfr[ks][1], acc[1][1], 0, 0, 0);
                }
            } else {
                const float* ap = x + ((size_t)t * BB + aRow) * DD + kh * 256 + sub;
                #pragma unroll
                for (int ks = 0; ks < 8; ++ks) {
                    bf16x8 a0 = cvt8(ap + ks * 32);
                    bf16x8 a1 = cvt8(ap + 16 * DD + ks * 32);
                    acc[0][0] = __builtin_amdgcn_mfma_f32_16x16x32_bf16(a0, bfr[ks][0], acc[0][0], 0, 0, 0);
                    acc[0][1] = __builtin_amdgcn_mfma_f32_16x16x32_bf16(a0, bfr[ks][1], acc[0][1], 0, 0, 0);
                    acc[1][0] = __builtin_amdgcn_mfma_f32_16x16x32_bf16(a1, bfr[ks][0], acc[1][0], 0, 0, 0);
                    acc[1][1] = __builtin_amdgcn_mfma_f32_16x16x32_bf16(a1, bfr[ks][1], acc[1][1], 0, 0, 0);
                }
            }
        } else {
            // ---- h half of K ----
            if constexpr (MODE < 2) {
                // coherent loads from the h exchange buffer (L3-resident)
                const ushort_t* hb = hbuf + (size_t)(t & 1) * HB_ELEMS
                                   + (size_t)(((kh - 2) * 32 + lg)) * 512 + (size_t)aRow * 8;
                bf16x8 ha0[8], ha1[8];
                #pragma unroll
                for (int ks = 0; ks < 8; ++ks) {
                    ha0[ks] = load_coh16(hb + ks * 2048);
                    ha1[ks] = load_coh16(hb + ks * 2048 + 128);
                }
                asm volatile("s_waitcnt vmcnt(0)" ::: "memory");
                __builtin_amdgcn_sched_barrier(0);
                #pragma unroll
                for (int ks = 0; ks < 8; ++ks) {
                    acc[0][0] = __builtin_amdgcn_mfma_f32_16x16x32_bf16(ha0[ks], bfr[ks][0], acc[0][0], 0, 0, 0);
                    acc[0][1] = __builtin_amdgcn_mfma_f32_16x16x32_bf16(ha0[ks], bfr[ks][1], acc[0][1], 0, 0, 0);
                    acc[1][0] = __builtin_amdgcn_mfma_f32_16x16x32_bf16(ha1[ks], bfr[ks][0], acc[1][0], 0, 0, 0);
                    acc[1][1] = __builtin_amdgcn_mfma_f32_16x16x32_bf16(ha1[ks], bfr[ks][1], acc[1][1], 0, 0, 0);
                }
            } else {
                if (t > 0) {
                    const float* ap = out + ((size_t)(t - 1) * BB + aRow) * HH + (kh - 2) * 256 + sub;
                    #pragma unroll
                    for (int ks = 0; ks < 8; ++ks) {
                        bf16x8 a0 = cvt8(ap + ks * 32);
                        bf16x8 a1 = cvt8(ap + 16 * HH + ks * 32);
                        acc[0][0] = __builtin_amdgcn_mfma_f32_16x16x32_bf16(a0, bfr[ks][0], acc[0][0], 0, 0, 0);
                        acc[0][1] = __builtin_amdgcn_mfma_f32_16x16x32_bf16(a0, bfr[ks][1], acc[0][1], 0, 0, 0);
                        acc[1][0] = __builtin_amdgcn_mfma_f32_16x16x32_bf16(a1, bfr[ks][0], acc[1][0], 0, 0, 0);
                        acc[1][1] = __builtin_amdgcn_mfma_f32_16x16x32_bf16(a1, bfr[ks][1], acc[1][1], 0, 0, 0);
                    }
                }
            }
        }

        // ---- cross-wave K reduction (4-way) ----
        if (kh > 0) {
            #pragma unroll
            for (int mtl = 0; mtl < 2; ++mtl)
                #pragma unroll
                for (int nt = 0; nt < 2; ++nt)
                    #pragma unroll
                    for (int r = 0; r < 4; ++r) {
                        int row = mp * 32 + mtl * 16 + lg * 4 + r;
                        P[kh - 1][row * PSTR + nt * 16 + l15] = acc[mtl][nt][r];
                    }
        }
        __syncthreads();
        if (kh == 0) {
            #pragma unroll
            for (int mtl = 0; mtl < 2; ++mtl)
                #pragma unroll
                for (int nt = 0; nt < 2; ++nt)
                    #pragma unroll
                    for (int r = 0; r < 4; ++r) {
                        int row = mp * 32 + mtl * 16 + lg * 4 + r;
                        int idx = row * PSTR + nt * 16 + l15;
                        G[idx] = acc[mtl][nt][r] + P[0][idx] + P[1][idx] + P[2][idx];
                    }
        }
        __syncthreads();

        // ---- activations: thread owns (b_act, hcol = wg*8 + j_act) ----
        {
            float gf = G[b_act * PSTR +      j_act] + bfv;
            float gi = G[b_act * PSTR +  8 + j_act] + biv;
            float gg = G[b_act * PSTR + 16 + j_act] + bgv;
            float go = G[b_act * PSTR + 24 + j_act] + bov;
            float fg = fast_sigmoid(gf);
            float ig = fast_sigmoid(gi);
            float g2 = fast_tanh(gg);
            float og = fast_sigmoid(go);
            c_state = fg * c_state + ig * g2;
            float hv = og * fast_tanh(c_state);
            h_last = hv;
            out[((size_t)t * BB + b_act) * HH + wg * 8 + j_act] = hv;
            if constexpr (MODE < 2) {
                // WG's 512 h values form a contiguous 1KB block: elem = wg*512 + tid
                store_coh2(hbuf + (size_t)((t & 1) ^ 1) * HB_ELEMS + wg * 512 + tid,
                           (unsigned)f2bf(hv));
            }
        }

        // ---- grid barrier: relaxed atomics, no cache maintenance ----
        if constexpr (MODE < 2) {
            if (t != TT - 1) {
                asm volatile("s_waitcnt vmcnt(0)" ::: "memory");  // h stores visible at L3
                __syncthreads();
                if (tid == 0) {
                    __hip_atomic_fetch_add(&ctr[t], 1u, __ATOMIC_RELAXED, __HIP_MEMORY_SCOPE_AGENT);
                    if (!dead) {
                        int it = 0;
                        while (__hip_atomic_load(&ctr[t], __ATOMIC_RELAXED, __HIP_MEMORY_SCOPE_AGENT) < NWG) {
                            __builtin_amdgcn_s_sleep(1);
                            if (++it > SPIN_MAX) { dead = 1; break; }
                        }
                    }
                }
                __syncthreads();
            }
        }
    }

    // ---- hT, cT ----
    {
        size_t base = (size_t)TT * BB * HH;
        out[base + (size_t)b_act * HH + wg * 8 + j_act] = h_last;
        out[base + BB * HH + (size_t)b_act * HH + wg * 8 + j_act] = c_state;
    }
}

extern "C" void kernel_launch(void* const* d_in, const int* in_sizes, int n_in,
                              void* d_out, int out_size, void* d_ws, size_t ws_size,
                              hipStream_t stream) {
    const float* x   = (const float*)d_in[0];
    const float* Wf  = (const float*)d_in[1];
    const float* bf_ = (const float*)d_in[2];
    const float* Wi  = (const float*)d_in[3];
    const float* bi_ = (const float*)d_in[4];
    const float* Wg  = (const float*)d_in[5];
    const float* bg_ = (const float*)d_in[6];
    const float* Wo  = (const float*)d_in[7];
    const float* bo_ = (const float*)d_in[8];
    float* out = (float*)d_out;

    unsigned*  ctr  = (unsigned*)d_ws;                         // 512 * 4 B
    ushort_t*  hbuf = (ushort_t*)((char*)d_ws + 4096);         // 2 * 32768 bf16 = 128 KB
    ushort_t*  xbf  = (ushort_t*)((char*)d_ws + 262144);       // T*B*D bf16 (32 MB)

    const size_t need_small = 4096 + 2 * HB_ELEMS * sizeof(ushort_t);     // 135168 B
    const size_t need_full  = 262144 + (size_t)TT * BB * DD * sizeof(ushort_t);

    if (ws_size >= need_full) {
        hipMemsetAsync(d_ws, 0, need_small, stream);
        cvt_x<<<2048, 256, 0, stream>>>(x, xbf, TT * BB * DD);
        lstm_kernel<0><<<NWG, NTH, 0, stream>>>(x, xbf, Wf, bf_, Wi, bi_, Wg, bg_,
                                                Wo, bo_, out, ctr, hbuf, 0, TT);
    } else if (ws_size >= need_small) {
        hipMemsetAsync(d_ws, 0, need_small, stream);
        lstm_kernel<1><<<NWG, NTH, 0, stream>>>(x, xbf, Wf, bf_, Wi, bi_, Wg, bg_,
                                                Wo, bo_, out, ctr, hbuf, 0, TT);
    } else {
        // zero-workspace safety net: one launch per time step, stream-ordered
        for (int t = 0; t < TT; ++t)
            lstm_kernel<2><<<NWG, NTH, 0, stream>>>(x, xbf, Wf, bf_, Wi, bi_, Wg, bg_,
                                                    Wo, bo_, out, ctr, hbuf, t, t + 1);
    }
}